// Round 1
// baseline (531.379 us; speedup 1.0000x reference)
//
#include <hip/hip_runtime.h>

#define HW 16384
#define IGN 5
#define ROWS_TOTAL 12288
#define ANCH_ELEMS (ROWS_TOTAL * 256)

typedef __bf16 bf16x8 __attribute__((ext_vector_type(8)));
typedef float f32x4 __attribute__((ext_vector_type(4)));

// ---------------- prep: argmax(labels[0, ::8, ::8]) + inv_map init ----------------
__global__ void prep_kernel(const float* __restrict__ labels, int* __restrict__ y_hat,
                            int* __restrict__ inv) {
    int p = blockIdx.x * 256 + threadIdx.x;
    if (p >= HW) return;
    int pr = p >> 7, pc = p & 127;
    const float* lp = labels + ((size_t)(pr * 8) * 1024 + (size_t)pc * 8) * 5;
    float best = lp[0];
    int bi = 0;
#pragma unroll
    for (int c = 1; c < 5; ++c) {
        float v = lp[c];
        if (v > best) { best = v; bi = c; }
    }
    y_hat[p] = bi;
    inv[p] = -1;
}

// ---------------- per-class stratified stable selection (1 wave per class) -------
__global__ void select_kernel(const int* __restrict__ y_hat, const int* __restrict__ y,
                              int* __restrict__ inv, int* __restrict__ nsel) {
    int c = blockIdx.x;
    int lane = threadIdx.x;  // 0..63
    int mv = (c == 0) ? 4096 : 2048;
    int base = (c == 0) ? 0 : 4096 + (c - 1) * 2048;

    int nh = 0, ne = 0;
    for (int it = 0; it < HW / 64; ++it) {
        int p = it * 64 + lane;
        int yh = y_hat[p], yy = y[p];
        bool hard = (yh == c) && (yy != c);
        bool easy = (yh == c) && (yy == c);
        nh += __popcll(__ballot(hard));
        ne += __popcll(__ballot(easy));
    }
    int cnt = nh + ne;
    int n_sel = (cnt > 1) ? ((cnt < mv) ? cnt : mv) : 0;
    int hk;
    if ((2 * nh >= n_sel) && (2 * ne >= n_sel)) hk = n_sel >> 1;
    else if (2 * nh >= n_sel) hk = n_sel - ne;
    else hk = nh;
    int ek = n_sel - hk;

    unsigned long long below = (1ull << lane) - 1ull;
    int hrun = 0, erun = 0;
    for (int it = 0; it < HW / 64; ++it) {
        int p = it * 64 + lane;
        int yh = y_hat[p], yy = y[p];
        bool hard = (yh == c) && (yy != c);
        bool easy = (yh == c) && (yy == c);
        unsigned long long mh = __ballot(hard);
        unsigned long long me = __ballot(easy);
        int ph = hrun + __popcll(mh & below);
        int pe = erun + __popcll(me & below);
        if (hard && ph < hk) inv[p] = base + ph;
        if (easy && pe < ek) inv[p] = base + hk + pe;
        hrun += __popcll(mh);
        erun += __popcll(me);
    }
    if (lane == 0) nsel[c] = n_sel;
}

// ---------------- transpose + f32->bf16 convert: feats[0] (512,16384) -> Xb (16384,512)
__global__ void conv_x_kernel(const float* __restrict__ F, __bf16* __restrict__ Xb) {
    __shared__ float t[32 * 33];
    int pb = blockIdx.x * 32, chb = blockIdx.y * 32;
    int tid = threadIdx.x;
    int il = tid & 31;
    int grp = tid >> 5;  // 0..7
#pragma unroll
    for (int it = 0; it < 4; ++it) {
        int ch = grp + it * 8;
        t[il * 33 + ch] = F[(size_t)(chb + ch) * HW + pb + il];
    }
    __syncthreads();
#pragma unroll
    for (int it = 0; it < 4; ++it) {
        int p = grp + it * 8;
        Xb[(size_t)(pb + p) * 512 + chb + il] = (__bf16)t[p * 33 + il];
    }
}

// ---------------- weight f32->bf16 convert (w1,w2,w3 fused) ----------------------
__global__ void conv_w_kernel(const float* __restrict__ w1, const float* __restrict__ w2,
                              const float* __restrict__ w3, __bf16* __restrict__ w1b,
                              __bf16* __restrict__ w2b, __bf16* __restrict__ w3b) {
    int i = blockIdx.x * 256 + threadIdx.x;
    if (i < 262144) w1b[i] = (__bf16)w1[i];
    else if (i < 393216) w2b[i - 262144] = (__bf16)w2[i - 262144];
    else if (i < 458752) w3b[i - 393216] = (__bf16)w3[i - 393216];
}

// ---------------- zero anchors + write y_ labels ---------------------------------
__global__ void fill_out_kernel(float* __restrict__ out, const int* __restrict__ nsel) {
    int idx = blockIdx.x * 256 + threadIdx.x;
    if (idx < ANCH_ELEMS / 4) {
        ((float4*)out)[idx] = make_float4(0.f, 0.f, 0.f, 0.f);
    } else {
        int r = idx - ANCH_ELEMS / 4;
        if (r < ROWS_TOTAL) {
            int c, rin;
            if (r < 4096) { c = 0; rin = r; }
            else { c = 1 + ((r - 4096) >> 11); rin = (r - 4096) & 2047; }
            out[ANCH_ELEMS + r] = (float)(rin < nsel[c] ? c : IGN);
        }
    }
}

// ---------------- GEMM: C(MxN) = act(A(MxK) * W(NxK)^T + bias), bf16 in/out ------
// 128x128 block tile, BK=32, 4 waves (2x2), each wave 64x64 via 4x4 mfma 16x16x32
__global__ __launch_bounds__(256) void gemm_bt(const __bf16* __restrict__ A,
                                               const __bf16* __restrict__ Bw,
                                               const float* __restrict__ bias,
                                               __bf16* __restrict__ C, int M, int N, int K,
                                               int leaky) {
    const int BK = 32;
    __shared__ __bf16 As[128 * 32];
    __shared__ __bf16 Bs[128 * 32];
    int tid = threadIdx.x;
    int lane = tid & 63, wave = tid >> 6;
    int wm = (wave >> 1) * 64, wn = (wave & 1) * 64;
    int mb = blockIdx.y * 128, nb = blockIdx.x * 128;
    int l15 = lane & 15, quad = lane >> 4;

    f32x4 acc[4][4] = {};

    for (int kt = 0; kt < K; kt += BK) {
#pragma unroll
        for (int r = 0; r < 2; ++r) {
            int cc = tid + r * 256;
            int row = cc >> 2, ko = (cc & 3) * 8;
            *(uint4*)(As + row * BK + ko) =
                *(const uint4*)(A + (size_t)(mb + row) * K + kt + ko);
            *(uint4*)(Bs + row * BK + ko) =
                *(const uint4*)(Bw + (size_t)(nb + row) * K + kt + ko);
        }
        __syncthreads();
        bf16x8 af[4], bq[4];
#pragma unroll
        for (int i = 0; i < 4; ++i)
            af[i] = *(const bf16x8*)(As + (wm + i * 16 + l15) * BK + quad * 8);
#pragma unroll
        for (int j = 0; j < 4; ++j)
            bq[j] = *(const bf16x8*)(Bs + (wn + j * 16 + l15) * BK + quad * 8);
#pragma unroll
        for (int i = 0; i < 4; ++i)
#pragma unroll
            for (int j = 0; j < 4; ++j)
                acc[i][j] = __builtin_amdgcn_mfma_f32_16x16x32_bf16(af[i], bq[j], acc[i][j], 0, 0, 0);
        __syncthreads();
    }

#pragma unroll
    for (int i = 0; i < 4; ++i) {
#pragma unroll
        for (int j = 0; j < 4; ++j) {
            int col = nb + wn + j * 16 + l15;
            float bv = bias[col];
#pragma unroll
            for (int r = 0; r < 4; ++r) {
                int row = mb + wm + i * 16 + quad * 4 + r;
                float v = acc[i][j][r] + bv;
                if (leaky) v = (v >= 0.f) ? v : 0.2f * v;
                C[(size_t)row * N + col] = (__bf16)v;
            }
        }
    }
}

// ---------------- GEMM3 (K=256,N=256) + row-norm + scatter to output -------------
// block: 64 pixels x 256 outs; 4 waves, wave w covers cols w*64..w*64+63
__global__ __launch_bounds__(256) void gemm3_norm_scatter(const __bf16* __restrict__ A,
                                                          const __bf16* __restrict__ W,
                                                          const float* __restrict__ bias,
                                                          const int* __restrict__ inv,
                                                          float* __restrict__ out) {
    const int BK = 32, K = 256;
    __shared__ __bf16 As[64 * 32];
    __shared__ __bf16 Bs[256 * 32];
    __shared__ __bf16 lo[64 * 264];
    __shared__ float nrm[64];
    int tid = threadIdx.x;
    int lane = tid & 63, wave = tid >> 6;
    int l15 = lane & 15, quad = lane >> 4;
    int mb = blockIdx.x * 64;
    int wn = wave * 64;

    if (tid < 64) nrm[tid] = 0.f;

    f32x4 acc[4][4] = {};

    for (int kt = 0; kt < K; kt += BK) {
        {
            int row = tid >> 2, ko = (tid & 3) * 8;
            *(uint4*)(As + row * BK + ko) =
                *(const uint4*)(A + (size_t)(mb + row) * K + kt + ko);
        }
#pragma unroll
        for (int r = 0; r < 4; ++r) {
            int cc = tid + r * 256;
            int row = cc >> 2, ko = (cc & 3) * 8;
            *(uint4*)(Bs + row * BK + ko) = *(const uint4*)(W + (size_t)row * K + kt + ko);
        }
        __syncthreads();
        bf16x8 af[4], bq[4];
#pragma unroll
        for (int i = 0; i < 4; ++i)
            af[i] = *(const bf16x8*)(As + (i * 16 + l15) * BK + quad * 8);
#pragma unroll
        for (int j = 0; j < 4; ++j)
            bq[j] = *(const bf16x8*)(Bs + (wn + j * 16 + l15) * BK + quad * 8);
#pragma unroll
        for (int i = 0; i < 4; ++i)
#pragma unroll
            for (int j = 0; j < 4; ++j)
                acc[i][j] = __builtin_amdgcn_mfma_f32_16x16x32_bf16(af[i], bq[j], acc[i][j], 0, 0, 0);
        __syncthreads();
    }

    // bias add, stash to LDS (bf16), accumulate sum-of-squares per pixel row
#pragma unroll
    for (int i = 0; i < 4; ++i) {
#pragma unroll
        for (int r = 0; r < 4; ++r) {
            int row = i * 16 + quad * 4 + r;
            float s = 0.f;
#pragma unroll
            for (int j = 0; j < 4; ++j) {
                int col = wn + j * 16 + l15;
                float v = acc[i][j][r] + bias[col];
                lo[row * 264 + col] = (__bf16)v;
                s += v * v;
            }
            atomicAdd(&nrm[row], s);
        }
    }
    __syncthreads();
    if (tid < 64) nrm[tid] = 1.0f / fmaxf(sqrtf(nrm[tid]), 1e-12f);
    __syncthreads();

    for (int r = 0; r < 64; ++r) {
        int orow = inv[mb + r];
        if (orow >= 0) out[(size_t)orow * 256 + tid] = (float)lo[r * 264 + tid] * nrm[r];
    }
}

extern "C" void kernel_launch(void* const* d_in, const int* in_sizes, int n_in,
                              void* d_out, int out_size, void* d_ws, size_t ws_size,
                              hipStream_t stream) {
    const float* feats = (const float*)d_in[0];
    const float* labels = (const float*)d_in[1];
    const int* predicts = (const int*)d_in[2];
    const float* w1 = (const float*)d_in[3];
    const float* b1 = (const float*)d_in[4];
    const float* w2 = (const float*)d_in[5];
    const float* b2 = (const float*)d_in[6];
    const float* w3 = (const float*)d_in[7];
    const float* b3 = (const float*)d_in[8];
    float* out = (float*)d_out;
    char* ws = (char*)d_ws;

    int* y_hat = (int*)(ws + 0);
    int* inv = (int*)(ws + (64 << 10));
    int* nsel = (int*)(ws + (128 << 10));
    __bf16* w1b = (__bf16*)(ws + (256 << 10));
    __bf16* w2b = (__bf16*)(ws + (768 << 10));
    __bf16* w3b = (__bf16*)(ws + (1024 << 10));
    __bf16* Xb = (__bf16*)(ws + (2ull << 20));   // 16384x512 bf16 = 16MB
    __bf16* H1 = (__bf16*)(ws + (18ull << 20));  // 16384x512 bf16 = 16MB
    __bf16* H2 = (__bf16*)(ws + (34ull << 20));  // 16384x256 bf16 = 8MB

    prep_kernel<<<64, 256, 0, stream>>>(labels, y_hat, inv);
    select_kernel<<<5, 64, 0, stream>>>(y_hat, predicts, inv, nsel);
    conv_x_kernel<<<dim3(512, 16), 256, 0, stream>>>(feats, Xb);
    conv_w_kernel<<<1792, 256, 0, stream>>>(w1, w2, w3, w1b, w2b, w3b);
    fill_out_kernel<<<3120, 256, 0, stream>>>(out, nsel);
    gemm_bt<<<dim3(4, 128), 256, 0, stream>>>(Xb, w1b, b1, H1, HW, 512, 512, 1);
    gemm_bt<<<dim3(2, 128), 256, 0, stream>>>(H1, w2b, b2, H2, HW, 256, 512, 1);
    gemm3_norm_scatter<<<256, 256, 0, stream>>>(H2, w3b, b3, inv, out);
}

// Round 2
// 447.707 us; speedup vs baseline: 1.1869x; 1.1869x over previous
//
#include <hip/hip_runtime.h>

#define HW 16384
#define IGN 5
#define ROWS_TOTAL 12288
#define ANCH_ELEMS (ROWS_TOTAL * 256)

typedef __bf16 bf16x8 __attribute__((ext_vector_type(8)));
typedef float f32x4 __attribute__((ext_vector_type(4)));
typedef unsigned long long ull;

#define GLDS16(g, l)                                                                     \
    __builtin_amdgcn_global_load_lds((__attribute__((address_space(1))) const void*)(g), \
                                     (__attribute__((address_space(3))) void*)(l), 16, 0, 0)

// ---------------- prep: argmax(labels[0, ::8, ::8]) + per-chunk class masks ------
__global__ void prep_kernel(const float* __restrict__ labels, const int* __restrict__ predicts,
                            int* __restrict__ y_hat, ull* __restrict__ maskH,
                            ull* __restrict__ maskE) {
    int p = blockIdx.x * 256 + threadIdx.x;
    int pr = p >> 7, pc = p & 127;
    const float* lp = labels + ((size_t)(pr * 8) * 1024 + (size_t)(pc * 8)) * 5;
    float best = lp[0];
    int bi = 0;
#pragma unroll
    for (int c = 1; c < 5; ++c) {
        float v = lp[c];
        if (v > best) { best = v; bi = c; }
    }
    y_hat[p] = bi;
    int yy = predicts[p];
    int chunk = p >> 6;
    int lane = threadIdx.x & 63;
#pragma unroll
    for (int c = 0; c < 5; ++c) {
        ull mh = __ballot(bi == c && yy != c);
        ull me = __ballot(bi == c && yy == c);
        if (lane == 0) {
            maskH[c * 256 + chunk] = mh;
            maskE[c * 256 + chunk] = me;
        }
    }
}

// ---------------- scan: per-class prefix over 256 chunks (wave c = class c) ------
__global__ void scan_kernel(const ull* __restrict__ maskH, const ull* __restrict__ maskE,
                            int* __restrict__ baseH, int* __restrict__ baseE,
                            int* __restrict__ nsel, int* __restrict__ hkA,
                            int* __restrict__ ekA) {
    int c = threadIdx.x >> 6;
    int lane = threadIdx.x & 63;
    if (c >= 5) return;
    int ph[4], pe[4];
    int sh = 0, se = 0;
#pragma unroll
    for (int k = 0; k < 4; ++k) {
        int ch = lane * 4 + k;
        ph[k] = sh;
        sh += __popcll(maskH[c * 256 + ch]);
        pe[k] = se;
        se += __popcll(maskE[c * 256 + ch]);
    }
    int incH = sh, incE = se;
#pragma unroll
    for (int d = 1; d < 64; d <<= 1) {
        int t = __shfl_up(incH, d);
        if (lane >= d) incH += t;
        t = __shfl_up(incE, d);
        if (lane >= d) incE += t;
    }
    int exH = incH - sh, exE = incE - se;
#pragma unroll
    for (int k = 0; k < 4; ++k) {
        baseH[c * 256 + lane * 4 + k] = exH + ph[k];
        baseE[c * 256 + lane * 4 + k] = exE + pe[k];
    }
    int nh = __shfl(incH, 63), ne = __shfl(incE, 63);
    if (lane == 0) {
        int mv = (c == 0) ? 4096 : 2048;
        int cnt = nh + ne;
        int n_sel = (cnt > 1) ? ((cnt < mv) ? cnt : mv) : 0;
        int hk;
        if ((2 * nh >= n_sel) && (2 * ne >= n_sel)) hk = n_sel >> 1;
        else if (2 * nh >= n_sel) hk = n_sel - ne;
        else hk = nh;
        nsel[c] = n_sel;
        hkA[c] = hk;
        ekA[c] = n_sel - hk;
    }
}

// ---------------- write_inv: fully parallel pixel -> output-row map --------------
__global__ void write_inv_kernel(const int* __restrict__ y_hat, const int* __restrict__ predicts,
                                 const ull* __restrict__ maskH, const ull* __restrict__ maskE,
                                 const int* __restrict__ baseH, const int* __restrict__ baseE,
                                 const int* __restrict__ hkA, const int* __restrict__ ekA,
                                 int* __restrict__ inv) {
    int p = blockIdx.x * 256 + threadIdx.x;
    int chunk = p >> 6;
    int lane = threadIdx.x & 63;
    int c = y_hat[p];
    ull mh = maskH[c * 256 + chunk];
    ull me = maskE[c * 256 + chunk];
    ull below = (1ull << lane) - 1ull;
    int cls_base = (c == 0) ? 0 : 4096 + (c - 1) * 2048;
    int res = -1;
    if ((mh >> lane) & 1ull) {
        int pos = baseH[c * 256 + chunk] + __popcll(mh & below);
        if (pos < hkA[c]) res = cls_base + pos;
    } else if ((me >> lane) & 1ull) {
        int pos = baseE[c * 256 + chunk] + __popcll(me & below);
        if (pos < ekA[c]) res = cls_base + hkA[c] + pos;
    }
    inv[p] = res;
}

// ---------------- transpose + f32->bf16 convert: feats[0] (512,16384) -> Xb ------
__global__ void conv_x_kernel(const float* __restrict__ F, __bf16* __restrict__ Xb) {
    __shared__ float t[32 * 33];
    int pb = blockIdx.x * 32, chb = blockIdx.y * 32;
    int tid = threadIdx.x;
    int il = tid & 31;
    int grp = tid >> 5;  // 0..7
#pragma unroll
    for (int it = 0; it < 4; ++it) {
        int ch = grp + it * 8;
        t[il * 33 + ch] = F[(size_t)(chb + ch) * HW + pb + il];
    }
    __syncthreads();
#pragma unroll
    for (int it = 0; it < 4; ++it) {
        int p = grp + it * 8;
        Xb[(size_t)(pb + p) * 512 + chb + il] = (__bf16)t[p * 33 + il];
    }
}

// ---------------- weight f32->bf16 convert (w1,w2,w3 fused) ----------------------
__global__ void conv_w_kernel(const float* __restrict__ w1, const float* __restrict__ w2,
                              const float* __restrict__ w3, __bf16* __restrict__ w1b,
                              __bf16* __restrict__ w2b, __bf16* __restrict__ w3b) {
    int i = blockIdx.x * 256 + threadIdx.x;
    if (i < 262144) w1b[i] = (__bf16)w1[i];
    else if (i < 393216) w2b[i - 262144] = (__bf16)w2[i - 262144];
    else if (i < 458752) w3b[i - 393216] = (__bf16)w3[i - 393216];
}

// ---------------- zero anchors + write y_ labels ---------------------------------
__global__ void fill_out_kernel(float* __restrict__ out, const int* __restrict__ nsel) {
    int idx = blockIdx.x * 256 + threadIdx.x;
    if (idx < ANCH_ELEMS / 4) {
        ((float4*)out)[idx] = make_float4(0.f, 0.f, 0.f, 0.f);
    } else {
        int r = idx - ANCH_ELEMS / 4;
        if (r < ROWS_TOTAL) {
            int c, rin;
            if (r < 4096) { c = 0; rin = r; }
            else { c = 1 + ((r - 4096) >> 11); rin = (r - 4096) & 2047; }
            out[ANCH_ELEMS + r] = (float)(rin < nsel[c] ? c : IGN);
        }
    }
}

// ---------------- GEMM: C(MxN) = act(A(MxK) * W(NxK)^T + bias), bf16 in/out ------
// 128x128 block tile, BK=32, 4 waves (2x2), global_load_lds width-16 staging
__global__ __launch_bounds__(256) void gemm_bt(const __bf16* __restrict__ A,
                                               const __bf16* __restrict__ Bw,
                                               const float* __restrict__ bias,
                                               __bf16* __restrict__ C, int M, int N, int K,
                                               int leaky) {
    const int BK = 32;
    __shared__ __bf16 As[128 * 32];
    __shared__ __bf16 Bs[128 * 32];
    int tid = threadIdx.x;
    int lane = tid & 63;
    int wave_base = tid & 0xC0;  // wave*64, uniform per wave
    int wave = tid >> 6;
    int wm = (wave >> 1) * 64, wn = (wave & 1) * 64;
    int mb = blockIdx.y * 128, nb = blockIdx.x * 128;
    int l15 = lane & 15, quad = lane >> 4;

    f32x4 acc[4][4] = {};

    for (int kt = 0; kt < K; kt += BK) {
#pragma unroll
        for (int r = 0; r < 2; ++r) {
            int cc = tid + r * 256;
            int row = cc >> 2, ko = (cc & 3) * 8;
            GLDS16(A + (size_t)(mb + row) * K + kt + ko,
                   As + (size_t)(r * 256 + wave_base) * 8);
            GLDS16(Bw + (size_t)(nb + row) * K + kt + ko,
                   Bs + (size_t)(r * 256 + wave_base) * 8);
        }
        __syncthreads();
        bf16x8 af[4], bq[4];
#pragma unroll
        for (int i = 0; i < 4; ++i)
            af[i] = *(const bf16x8*)(As + (wm + i * 16 + l15) * BK + quad * 8);
#pragma unroll
        for (int j = 0; j < 4; ++j)
            bq[j] = *(const bf16x8*)(Bs + (wn + j * 16 + l15) * BK + quad * 8);
#pragma unroll
        for (int i = 0; i < 4; ++i)
#pragma unroll
            for (int j = 0; j < 4; ++j)
                acc[i][j] = __builtin_amdgcn_mfma_f32_16x16x32_bf16(af[i], bq[j], acc[i][j], 0, 0, 0);
        __syncthreads();
    }

#pragma unroll
    for (int i = 0; i < 4; ++i) {
#pragma unroll
        for (int j = 0; j < 4; ++j) {
            int col = nb + wn + j * 16 + l15;
            float bv = bias[col];
#pragma unroll
            for (int r = 0; r < 4; ++r) {
                int row = mb + wm + i * 16 + quad * 4 + r;
                float v = acc[i][j][r] + bv;
                if (leaky) v = (v >= 0.f) ? v : 0.2f * v;
                C[(size_t)row * N + col] = (__bf16)v;
            }
        }
    }
}

// ---------------- GEMM3 (K=256,N=256) + row-norm + scatter to output -------------
__global__ __launch_bounds__(256) void gemm3_norm_scatter(const __bf16* __restrict__ A,
                                                          const __bf16* __restrict__ W,
                                                          const float* __restrict__ bias,
                                                          const int* __restrict__ inv,
                                                          float* __restrict__ out) {
    const int BK = 32, K = 256;
    __shared__ __bf16 As[64 * 32];
    __shared__ __bf16 Bs[256 * 32];
    __shared__ __bf16 lo[64 * 264];
    __shared__ float nrm[64];
    int tid = threadIdx.x;
    int lane = tid & 63, wave = tid >> 6;
    int wave_base = tid & 0xC0;
    int l15 = lane & 15, quad = lane >> 4;
    int mb = blockIdx.x * 64;
    int wn = wave * 64;

    if (tid < 64) nrm[tid] = 0.f;

    f32x4 acc[4][4] = {};

    for (int kt = 0; kt < K; kt += BK) {
        {
            int row = tid >> 2, ko = (tid & 3) * 8;
            GLDS16(A + (size_t)(mb + row) * K + kt + ko, As + (size_t)wave_base * 8);
        }
#pragma unroll
        for (int r = 0; r < 4; ++r) {
            int cc = tid + r * 256;
            int row = cc >> 2, ko = (cc & 3) * 8;
            GLDS16(W + (size_t)row * K + kt + ko, Bs + (size_t)(r * 256 + wave_base) * 8);
        }
        __syncthreads();
        bf16x8 af[4], bq[4];
#pragma unroll
        for (int i = 0; i < 4; ++i)
            af[i] = *(const bf16x8*)(As + (i * 16 + l15) * BK + quad * 8);
#pragma unroll
        for (int j = 0; j < 4; ++j)
            bq[j] = *(const bf16x8*)(Bs + (wn + j * 16 + l15) * BK + quad * 8);
#pragma unroll
        for (int i = 0; i < 4; ++i)
#pragma unroll
            for (int j = 0; j < 4; ++j)
                acc[i][j] = __builtin_amdgcn_mfma_f32_16x16x32_bf16(af[i], bq[j], acc[i][j], 0, 0, 0);
        __syncthreads();
    }

#pragma unroll
    for (int i = 0; i < 4; ++i) {
#pragma unroll
        for (int r = 0; r < 4; ++r) {
            int row = i * 16 + quad * 4 + r;
            float s = 0.f;
#pragma unroll
            for (int j = 0; j < 4; ++j) {
                int col = wn + j * 16 + l15;
                float v = acc[i][j][r] + bias[col];
                lo[row * 264 + col] = (__bf16)v;
                s += v * v;
            }
            atomicAdd(&nrm[row], s);
        }
    }
    __syncthreads();
    if (tid < 64) nrm[tid] = 1.0f / fmaxf(sqrtf(nrm[tid]), 1e-12f);
    __syncthreads();

    for (int r = 0; r < 64; ++r) {
        int orow = inv[mb + r];
        if (orow >= 0) out[(size_t)orow * 256 + tid] = (float)lo[r * 264 + tid] * nrm[r];
    }
}

extern "C" void kernel_launch(void* const* d_in, const int* in_sizes, int n_in,
                              void* d_out, int out_size, void* d_ws, size_t ws_size,
                              hipStream_t stream) {
    const float* feats = (const float*)d_in[0];
    const float* labels = (const float*)d_in[1];
    const int* predicts = (const int*)d_in[2];
    const float* w1 = (const float*)d_in[3];
    const float* b1 = (const float*)d_in[4];
    const float* w2 = (const float*)d_in[5];
    const float* b2 = (const float*)d_in[6];
    const float* w3 = (const float*)d_in[7];
    const float* b3 = (const float*)d_in[8];
    float* out = (float*)d_out;
    char* ws = (char*)d_ws;

    int* y_hat = (int*)(ws + 0);                    // 64 KB
    int* inv = (int*)(ws + (64 << 10));             // 64 KB
    int* nsel = (int*)(ws + (128 << 10));           // 5 ints
    int* hkA = (int*)(ws + (128 << 10) + 64);
    int* ekA = (int*)(ws + (128 << 10) + 128);
    ull* maskH = (ull*)(ws + (136 << 10));          // 10 KB
    ull* maskE = (ull*)(ws + (148 << 10));          // 10 KB
    int* baseH = (int*)(ws + (160 << 10));          // 5 KB
    int* baseE = (int*)(ws + (168 << 10));          // 5 KB
    __bf16* w1b = (__bf16*)(ws + (256 << 10));
    __bf16* w2b = (__bf16*)(ws + (768 << 10));
    __bf16* w3b = (__bf16*)(ws + (1024 << 10));
    __bf16* Xb = (__bf16*)(ws + (2ull << 20));   // 16384x512 bf16 = 16MB
    __bf16* H1 = (__bf16*)(ws + (18ull << 20));  // 16384x512 bf16 = 16MB
    __bf16* H2 = (__bf16*)(ws + (34ull << 20));  // 16384x256 bf16 = 8MB

    prep_kernel<<<64, 256, 0, stream>>>(labels, predicts, y_hat, maskH, maskE);
    scan_kernel<<<1, 320, 0, stream>>>(maskH, maskE, baseH, baseE, nsel, hkA, ekA);
    write_inv_kernel<<<64, 256, 0, stream>>>(y_hat, predicts, maskH, maskE, baseH, baseE,
                                             hkA, ekA, inv);
    conv_x_kernel<<<dim3(512, 16), 256, 0, stream>>>(feats, Xb);
    conv_w_kernel<<<1792, 256, 0, stream>>>(w1, w2, w3, w1b, w2b, w3b);
    fill_out_kernel<<<3120, 256, 0, stream>>>(out, nsel);
    gemm_bt<<<dim3(4, 128), 256, 0, stream>>>(Xb, w1b, b1, H1, HW, 512, 512, 1);
    gemm_bt<<<dim3(2, 128), 256, 0, stream>>>(H1, w2b, b2, H2, HW, 256, 512, 1);
    gemm3_norm_scatter<<<256, 256, 0, stream>>>(H2, w3b, b3, inv, out);
}

// Round 3
// 428.817 us; speedup vs baseline: 1.2392x; 1.0441x over previous
//
#include <hip/hip_runtime.h>

#define HW 16384
#define IGN 5
#define ROWS_TOTAL 12288
#define ANCH_ELEMS (ROWS_TOTAL * 256)

typedef __bf16 bf16x8 __attribute__((ext_vector_type(8)));
typedef float f32x4 __attribute__((ext_vector_type(4)));
typedef unsigned long long ull;

#define GLDS16(g, l)                                                                     \
    __builtin_amdgcn_global_load_lds((__attribute__((address_space(1))) const void*)(g), \
                                     (__attribute__((address_space(3))) void*)(l), 16, 0, 0)

// element offset into a 64-elem-per-row bf16 tile, XOR-swizzled at 16B granularity
__device__ __forceinline__ int swz_off(int row, int chunk) {
    return row * 64 + ((chunk ^ (row & 7)) * 8);
}

// ---------------- prep: argmax(labels[0, ::8, ::8]) + per-chunk class masks ------
__global__ void prep_kernel(const float* __restrict__ labels, const int* __restrict__ predicts,
                            int* __restrict__ y_hat, ull* __restrict__ maskH,
                            ull* __restrict__ maskE, int* __restrict__ fwd) {
    int p = blockIdx.x * 256 + threadIdx.x;
    int pr = p >> 7, pc = p & 127;
    const float* lp = labels + ((size_t)(pr * 8) * 1024 + (size_t)(pc * 8)) * 5;
    float best = lp[0];
    int bi = 0;
#pragma unroll
    for (int c = 1; c < 5; ++c) {
        float v = lp[c];
        if (v > best) { best = v; bi = c; }
    }
    y_hat[p] = bi;
    if (p < ROWS_TOTAL) fwd[p] = -1;
    int yy = predicts[p];
    int chunk = p >> 6;
    int lane = threadIdx.x & 63;
#pragma unroll
    for (int c = 0; c < 5; ++c) {
        ull mh = __ballot(bi == c && yy != c);
        ull me = __ballot(bi == c && yy == c);
        if (lane == 0) {
            maskH[c * 256 + chunk] = mh;
            maskE[c * 256 + chunk] = me;
        }
    }
}

// ---------------- scan: per-class prefix over 256 chunks (wave c = class c) ------
__global__ void scan_kernel(const ull* __restrict__ maskH, const ull* __restrict__ maskE,
                            int* __restrict__ baseH, int* __restrict__ baseE,
                            int* __restrict__ nsel, int* __restrict__ hkA,
                            int* __restrict__ ekA) {
    int c = threadIdx.x >> 6;
    int lane = threadIdx.x & 63;
    if (c >= 5) return;
    int ph[4], pe[4];
    int sh = 0, se = 0;
#pragma unroll
    for (int k = 0; k < 4; ++k) {
        int ch = lane * 4 + k;
        ph[k] = sh;
        sh += __popcll(maskH[c * 256 + ch]);
        pe[k] = se;
        se += __popcll(maskE[c * 256 + ch]);
    }
    int incH = sh, incE = se;
#pragma unroll
    for (int d = 1; d < 64; d <<= 1) {
        int t = __shfl_up(incH, d);
        if (lane >= d) incH += t;
        t = __shfl_up(incE, d);
        if (lane >= d) incE += t;
    }
    int exH = incH - sh, exE = incE - se;
#pragma unroll
    for (int k = 0; k < 4; ++k) {
        baseH[c * 256 + lane * 4 + k] = exH + ph[k];
        baseE[c * 256 + lane * 4 + k] = exE + pe[k];
    }
    int nh = __shfl(incH, 63), ne = __shfl(incE, 63);
    if (lane == 0) {
        int mv = (c == 0) ? 4096 : 2048;
        int cnt = nh + ne;
        int n_sel = (cnt > 1) ? ((cnt < mv) ? cnt : mv) : 0;
        int hk;
        if ((2 * nh >= n_sel) && (2 * ne >= n_sel)) hk = n_sel >> 1;
        else if (2 * nh >= n_sel) hk = n_sel - ne;
        else hk = nh;
        nsel[c] = n_sel;
        hkA[c] = hk;
        ekA[c] = n_sel - hk;
    }
}

// ---------------- write_inv: fwd map (row->pixel) + y_ labels --------------------
__global__ void write_inv_kernel(const int* __restrict__ y_hat,
                                 const ull* __restrict__ maskH, const ull* __restrict__ maskE,
                                 const int* __restrict__ baseH, const int* __restrict__ baseE,
                                 const int* __restrict__ hkA, const int* __restrict__ ekA,
                                 const int* __restrict__ nsel, int* __restrict__ fwd,
                                 float* __restrict__ out) {
    int p = blockIdx.x * 256 + threadIdx.x;
    int chunk = p >> 6;
    int lane = threadIdx.x & 63;
    int c = y_hat[p];
    ull mh = maskH[c * 256 + chunk];
    ull me = maskE[c * 256 + chunk];
    ull below = (1ull << lane) - 1ull;
    int cls_base = (c == 0) ? 0 : 4096 + (c - 1) * 2048;
    int res = -1;
    if ((mh >> lane) & 1ull) {
        int pos = baseH[c * 256 + chunk] + __popcll(mh & below);
        if (pos < hkA[c]) res = cls_base + pos;
    } else if ((me >> lane) & 1ull) {
        int pos = baseE[c * 256 + chunk] + __popcll(me & below);
        if (pos < ekA[c]) res = cls_base + hkA[c] + pos;
    }
    if (res >= 0) fwd[res] = p;
    // y_ labels
    if (p < ROWS_TOTAL) {
        int cc, rin;
        if (p < 4096) { cc = 0; rin = p; }
        else { cc = 1 + ((p - 4096) >> 11); rin = (p - 4096) & 2047; }
        out[ANCH_ELEMS + p] = (float)(rin < nsel[cc] ? cc : IGN);
    }
}

// ---------------- transpose + f32->bf16 convert: feats[0] (512,16384) -> Xb ------
__global__ void conv_x_kernel(const float* __restrict__ F, __bf16* __restrict__ Xb) {
    __shared__ float t[32 * 33];
    int pb = blockIdx.x * 32, chb = blockIdx.y * 32;
    int tid = threadIdx.x;
    int il = tid & 31;
    int grp = tid >> 5;  // 0..7
#pragma unroll
    for (int it = 0; it < 4; ++it) {
        int ch = grp + it * 8;
        t[il * 33 + ch] = F[(size_t)(chb + ch) * HW + pb + il];
    }
    __syncthreads();
#pragma unroll
    for (int it = 0; it < 4; ++it) {
        int p = grp + it * 8;
        Xb[(size_t)(pb + p) * 512 + chb + il] = (__bf16)t[p * 33 + il];
    }
}

// ---------------- weight f32->bf16 convert (w1,w2,w3 fused) ----------------------
__global__ void conv_w_kernel(const float* __restrict__ w1, const float* __restrict__ w2,
                              const float* __restrict__ w3, __bf16* __restrict__ w1b,
                              __bf16* __restrict__ w2b, __bf16* __restrict__ w3b) {
    int i = blockIdx.x * 256 + threadIdx.x;
    if (i < 262144) w1b[i] = (__bf16)w1[i];
    else if (i < 393216) w2b[i - 262144] = (__bf16)w2[i - 262144];
    else if (i < 458752) w3b[i - 393216] = (__bf16)w3[i - 393216];
}

// ---------------- GEMM: C = act(A[fwd] * W^T + bias), 64x128 tile, BK=64 ---------
// waves 2x2 (32 rows x 64 cols each); XOR-swizzled LDS; optional row gather
__global__ __launch_bounds__(256) void gemm_bt(const __bf16* __restrict__ A,
                                               const int* __restrict__ fwd,
                                               const __bf16* __restrict__ Bw,
                                               const float* __restrict__ bias,
                                               __bf16* __restrict__ C, int N, int K,
                                               int leaky) {
    const int BK = 64;
    __shared__ __bf16 As[64 * 64];
    __shared__ __bf16 Bs[128 * 64];
    int tid = threadIdx.x;
    int lane = tid & 63;
    int wave_base = tid & 0xC0;  // wave*64, uniform per wave
    int wave = tid >> 6;
    int wm = (wave >> 1) * 32, wn = (wave & 1) * 64;
    int mb = blockIdx.y * 64, nb = blockIdx.x * 128;
    int l15 = lane & 15, quad = lane >> 4;

    // per-thread staging source rows (constant across K-loop)
    const __bf16* srcA[2];
    const __bf16* srcB[4];
#pragma unroll
    for (int r = 0; r < 2; ++r) {
        int cc = tid + r * 256;           // 0..511
        int row = cc >> 3, ch = cc & 7;   // row 0..63, 16B chunk 0..7
        int g = mb + row;
        int pix = fwd ? fwd[g] : g;
        if (pix < 0) pix = 0;
        srcA[r] = A + (size_t)pix * K + ((ch ^ (row & 7)) * 8);
    }
#pragma unroll
    for (int r = 0; r < 4; ++r) {
        int cc = tid + r * 256;           // 0..1023
        int row = cc >> 3, ch = cc & 7;   // row 0..127
        srcB[r] = Bw + (size_t)(nb + row) * K + ((ch ^ (row & 7)) * 8);
    }

    f32x4 acc[2][4] = {};

    for (int kt = 0; kt < K; kt += BK) {
#pragma unroll
        for (int r = 0; r < 2; ++r)
            GLDS16(srcA[r] + kt, As + (size_t)(r * 256 + wave_base) * 8);
#pragma unroll
        for (int r = 0; r < 4; ++r)
            GLDS16(srcB[r] + kt, Bs + (size_t)(r * 256 + wave_base) * 8);
        __syncthreads();
#pragma unroll
        for (int kk = 0; kk < 2; ++kk) {  // two 32-wide K-steps
            bf16x8 af[2], bq[4];
#pragma unroll
            for (int i = 0; i < 2; ++i)
                af[i] = *(const bf16x8*)(As + swz_off(wm + i * 16 + l15, quad + kk * 4));
#pragma unroll
            for (int j = 0; j < 4; ++j)
                bq[j] = *(const bf16x8*)(Bs + swz_off(wn + j * 16 + l15, quad + kk * 4));
#pragma unroll
            for (int i = 0; i < 2; ++i)
#pragma unroll
                for (int j = 0; j < 4; ++j)
                    acc[i][j] = __builtin_amdgcn_mfma_f32_16x16x32_bf16(af[i], bq[j], acc[i][j], 0, 0, 0);
        }
        __syncthreads();
    }

#pragma unroll
    for (int i = 0; i < 2; ++i) {
#pragma unroll
        for (int j = 0; j < 4; ++j) {
            int col = nb + wn + j * 16 + l15;
            float bv = bias[col];
#pragma unroll
            for (int r = 0; r < 4; ++r) {
                int row = mb + wm + i * 16 + quad * 4 + r;
                float v = acc[i][j][r] + bv;
                if (leaky) v = (v >= 0.f) ? v : 0.2f * v;
                C[(size_t)row * N + col] = (__bf16)v;
            }
        }
    }
}

// ---------------- GEMM3 (K=256,N=256) + row-norm + direct contiguous write -------
// block: 64 output rows x 256 cols; 4 waves (64x64 each); BK=64 swizzled
__global__ __launch_bounds__(256) void gemm3_norm(const __bf16* __restrict__ A,
                                                  const __bf16* __restrict__ W,
                                                  const float* __restrict__ bias,
                                                  const int* __restrict__ fwd,
                                                  float* __restrict__ out) {
    const int BK = 64, K = 256;
    __shared__ __bf16 As[64 * 64];
    __shared__ __bf16 Bs[256 * 64];
    __shared__ __bf16 lo[64 * 264];
    __shared__ float nrm[64];
    int tid = threadIdx.x;
    int lane = tid & 63, wave = tid >> 6;
    int wave_base = tid & 0xC0;
    int l15 = lane & 15, quad = lane >> 4;
    int mb = blockIdx.x * 64;
    int wn = wave * 64;

    if (tid < 64) nrm[tid] = 0.f;

    const __bf16* srcA[2];
    const __bf16* srcB[8];
#pragma unroll
    for (int r = 0; r < 2; ++r) {
        int cc = tid + r * 256;
        int row = cc >> 3, ch = cc & 7;
        srcA[r] = A + (size_t)(mb + row) * K + ((ch ^ (row & 7)) * 8);
    }
#pragma unroll
    for (int r = 0; r < 8; ++r) {
        int cc = tid + r * 256;           // 0..2047
        int row = cc >> 3, ch = cc & 7;   // row 0..255
        srcB[r] = W + (size_t)row * K + ((ch ^ (row & 7)) * 8);
    }

    f32x4 acc[4][4] = {};

    for (int kt = 0; kt < K; kt += BK) {
#pragma unroll
        for (int r = 0; r < 2; ++r)
            GLDS16(srcA[r] + kt, As + (size_t)(r * 256 + wave_base) * 8);
#pragma unroll
        for (int r = 0; r < 8; ++r)
            GLDS16(srcB[r] + kt, Bs + (size_t)(r * 256 + wave_base) * 8);
        __syncthreads();
#pragma unroll
        for (int kk = 0; kk < 2; ++kk) {
            bf16x8 af[4], bq[4];
#pragma unroll
            for (int i = 0; i < 4; ++i)
                af[i] = *(const bf16x8*)(As + swz_off(i * 16 + l15, quad + kk * 4));
#pragma unroll
            for (int j = 0; j < 4; ++j)
                bq[j] = *(const bf16x8*)(Bs + swz_off(wn + j * 16 + l15, quad + kk * 4));
#pragma unroll
            for (int i = 0; i < 4; ++i)
#pragma unroll
                for (int j = 0; j < 4; ++j)
                    acc[i][j] = __builtin_amdgcn_mfma_f32_16x16x32_bf16(af[i], bq[j], acc[i][j], 0, 0, 0);
        }
        __syncthreads();
    }

    // bias add, stash to LDS (bf16), accumulate sum-of-squares per row
#pragma unroll
    for (int i = 0; i < 4; ++i) {
#pragma unroll
        for (int r = 0; r < 4; ++r) {
            int row = i * 16 + quad * 4 + r;
            float s = 0.f;
#pragma unroll
            for (int j = 0; j < 4; ++j) {
                int col = wn + j * 16 + l15;
                float v = acc[i][j][r] + bias[col];
                lo[row * 264 + col] = (__bf16)v;
                s += v * v;
            }
            atomicAdd(&nrm[row], s);
        }
    }
    __syncthreads();
    if (tid < 64) {
        // fold validity mask into the norm factor: invalid rows -> exact 0 output
        float f = 1.0f / fmaxf(sqrtf(nrm[tid]), 1e-12f);
        nrm[tid] = (fwd[mb + tid] >= 0) ? f : 0.f;
    }
    __syncthreads();

#pragma unroll 4
    for (int r = 0; r < 64; ++r) {
        out[(size_t)(mb + r) * 256 + tid] = (float)lo[r * 264 + tid] * nrm[r];
    }
}

extern "C" void kernel_launch(void* const* d_in, const int* in_sizes, int n_in,
                              void* d_out, int out_size, void* d_ws, size_t ws_size,
                              hipStream_t stream) {
    const float* feats = (const float*)d_in[0];
    const float* labels = (const float*)d_in[1];
    const int* predicts = (const int*)d_in[2];
    const float* w1 = (const float*)d_in[3];
    const float* b1 = (const float*)d_in[4];
    const float* w2 = (const float*)d_in[5];
    const float* b2 = (const float*)d_in[6];
    const float* w3 = (const float*)d_in[7];
    const float* b3 = (const float*)d_in[8];
    float* out = (float*)d_out;
    char* ws = (char*)d_ws;

    int* y_hat = (int*)(ws + 0);           // 64 KB
    int* fwd = (int*)(ws + (64 << 10));    // 48 KB (12288 ints)
    int* nsel = (int*)(ws + (128 << 10));  // 5 ints
    int* hkA = (int*)(ws + (128 << 10) + 64);
    int* ekA = (int*)(ws + (128 << 10) + 128);
    ull* maskH = (ull*)(ws + (136 << 10));  // 10 KB
    ull* maskE = (ull*)(ws + (148 << 10));  // 10 KB
    int* baseH = (int*)(ws + (160 << 10));  // 5 KB
    int* baseE = (int*)(ws + (168 << 10));  // 5 KB
    __bf16* w1b = (__bf16*)(ws + (256 << 10));
    __bf16* w2b = (__bf16*)(ws + (768 << 10));
    __bf16* w3b = (__bf16*)(ws + (1024 << 10));
    __bf16* Xb = (__bf16*)(ws + (2ull << 20));   // 16384x512 bf16 = 16MB
    __bf16* H1 = (__bf16*)(ws + (18ull << 20));  // 12288x512 bf16 = 12MB
    __bf16* H2 = (__bf16*)(ws + (34ull << 20));  // 12288x256 bf16 = 6MB

    prep_kernel<<<64, 256, 0, stream>>>(labels, predicts, y_hat, maskH, maskE, fwd);
    scan_kernel<<<1, 320, 0, stream>>>(maskH, maskE, baseH, baseE, nsel, hkA, ekA);
    write_inv_kernel<<<64, 256, 0, stream>>>(y_hat, maskH, maskE, baseH, baseE, hkA, ekA,
                                             nsel, fwd, out);
    conv_x_kernel<<<dim3(512, 16), 256, 0, stream>>>(feats, Xb);
    conv_w_kernel<<<1792, 256, 0, stream>>>(w1, w2, w3, w1b, w2b, w3b);
    gemm_bt<<<dim3(4, 192), 256, 0, stream>>>(Xb, fwd, w1b, b1, H1, 512, 512, 1);
    gemm_bt<<<dim3(2, 192), 256, 0, stream>>>(H1, nullptr, w2b, b2, H2, 256, 512, 1);
    gemm3_norm<<<192, 256, 0, stream>>>(H2, w3b, b3, fwd, out);
}